// Round 16
// baseline (761.773 us; speedup 1.0000x reference)
//
#include <hip/hip_runtime.h>
#include <hip/hip_bf16.h>

// Fused LN -> QKV projection (bf16 MFMA, 256^2, register-pipelined 1-barrier
// K-loop: set2 reads under cluster1, stage+next-tile reads under cluster2,
// B-registers parity-duplicated), 2D-clustered XCD mapping, RoPE fused epilogue.
// x:(2,4096,2048) f32; wq/wk/wv:(2048,2048) f32 row-major [e][d]; out: q,k,v
// each (2,16,4096,128) f32 concatenated.

typedef float f32x4 __attribute__((ext_vector_type(4)));
typedef __bf16 bf16x8 __attribute__((ext_vector_type(8)));
typedef __bf16 bf16x4 __attribute__((ext_vector_type(4)));

#define DM    2048
#define NSEQ  4096
#define NH    16
#define HD    128
#define NROWS 8192
#define MAT_ELEMS (2ull*NH*NSEQ*HD)

// ---------- async global->LDS (16B/lane, wave-uniform LDS base) --------------
typedef __attribute__((address_space(1))) const void GV;
typedef __attribute__((address_space(3))) void LV;
__device__ __forceinline__ void gload_lds16(const void* g, void* l) {
    __builtin_amdgcn_global_load_lds((GV*)g, (LV*)l, 16, 0, 0);
}

// ------------- LayerNorm + weight f32->bf16 cast, single launch --------------
__global__ __launch_bounds__(256)
void lncvt_kernel(const float* __restrict__ x, const float* __restrict__ g,
                  const float* __restrict__ be,
                  const float* __restrict__ wq, const float* __restrict__ wk,
                  const float* __restrict__ wv,
                  __bf16* __restrict__ xnb, __bf16* __restrict__ wb) {
    int bid = blockIdx.x;
    int tid = threadIdx.x;
    if (bid < NROWS) {
        int row = bid;
        const float4* xr = (const float4*)(x + (size_t)row * DM);
        float4 v0 = xr[tid];
        float4 v1 = xr[tid + 256];
        float s  = v0.x + v0.y + v0.z + v0.w + v1.x + v1.y + v1.z + v1.w;
        float ss = v0.x*v0.x + v0.y*v0.y + v0.z*v0.z + v0.w*v0.w
                 + v1.x*v1.x + v1.y*v1.y + v1.z*v1.z + v1.w*v1.w;
#pragma unroll
        for (int o = 32; o > 0; o >>= 1) {
            s  += __shfl_down(s, o);
            ss += __shfl_down(ss, o);
        }
        __shared__ float red[10];
        int wave = tid >> 6, lane = tid & 63;
        if (lane == 0) { red[wave] = s; red[4 + wave] = ss; }
        __syncthreads();
        if (tid == 0) {
            float S  = red[0] + red[1] + red[2] + red[3];
            float SS = red[4] + red[5] + red[6] + red[7];
            float mu  = S * (1.0f / DM);
            float var = SS * (1.0f / DM) - mu * mu;
            red[8] = mu;
            red[9] = rsqrtf(var + 1e-5f);
        }
        __syncthreads();
        float mu = red[8], rs = red[9];

        const float4* gp = (const float4*)g;
        const float4* bp = (const float4*)be;
        bf16x4* orow = (bf16x4*)(xnb + (size_t)row * DM);
        {
            float4 g0 = gp[tid], b0 = bp[tid];
            bf16x4 o;
            o[0] = (__bf16)((v0.x - mu) * rs * g0.x + b0.x);
            o[1] = (__bf16)((v0.y - mu) * rs * g0.y + b0.y);
            o[2] = (__bf16)((v0.z - mu) * rs * g0.z + b0.z);
            o[3] = (__bf16)((v0.w - mu) * rs * g0.w + b0.w);
            orow[tid] = o;
        }
        {
            float4 g1 = gp[tid + 256], b1 = bp[tid + 256];
            bf16x4 o;
            o[0] = (__bf16)((v1.x - mu) * rs * g1.x + b1.x);
            o[1] = (__bf16)((v1.y - mu) * rs * g1.y + b1.y);
            o[2] = (__bf16)((v1.z - mu) * rs * g1.z + b1.z);
            o[3] = (__bf16)((v1.w - mu) * rs * g1.w + b1.w);
            orow[tid + 256] = o;
        }
    } else {
        int cb = bid - NROWS;                   // 0..6143
        const float* a = (cb < 2048) ? wq : (cb < 4096) ? wk : wv;
        size_t base = ((size_t)(cb & 2047) * 256 + tid) * 8;
        float4 v0 = *(const float4*)(a + base);
        float4 v1 = *(const float4*)(a + base + 4);
        bf16x8 r;
        r[0] = (__bf16)v0.x; r[1] = (__bf16)v0.y; r[2] = (__bf16)v0.z; r[3] = (__bf16)v0.w;
        r[4] = (__bf16)v1.x; r[5] = (__bf16)v1.y; r[6] = (__bf16)v1.z; r[7] = (__bf16)v1.w;
        *(bf16x8*)(wb + (size_t)(cb >> 11) * 4194304 + base) = r;
    }
}

// ======  256x256 QKV GEMM, register-pipelined, 1 barrier per K-tile  =========
// Tile 256x256, BK=64, 8 waves (2Mx4N), LDS 128KiB dbuf, XOR-swizzle
// (R12 addressing, 0 conflicts measured).
// Register sets: a_lo (A m0-3), a_hi (A m4-7), B duplicated by parity
// (bE*/bO*).  Body(kt), P=kt&1, Q=1-P, BC=parity-kt B, BN=other:
//   issue a_hi(kt) reads (8)                [port works under cluster1]
//   cluster1: 32 MFMA (a_lo x BC)           [compiler counted-lgkm gates a_lo]
//   lgkmcnt(0)                              [ALL my P-reads in registers]
//   vmcnt(0)                                [U(kt+1) landed; free: issued ~1
//                                            body (~3000cy) ago, nothing newer]
//   BAR                                     [=> all waves' P-reads in regs AND
//                                            U(kt+1) landed, collectively]
//   stage U(kt+2)->P (8 gloads)             [P write-safe by the BAR]
//   issue set1(kt+1) = a_lo+BN from Q (16)  [port works under cluster2]
//   cluster2: 32 MFMA (a_hi x BC)           [register-only]
// Waits are exact: prologue VM8 (U(0) landed, U(1) outstanding) + BAR.
// Tail: kt30 no stage; kt31 no stage/prefetch (vmcnt(0) free).

__device__ __forceinline__ void loadA4(bf16x8 (&a)[4][2], const __bf16* Sp,
                                       int base, int mb, int o0) {
#pragma unroll
    for (int mi = 0; mi < 4; mi++)
#pragma unroll
        for (int ks = 0; ks < 2; ks++)
            a[mi][ks] = *(const bf16x8*)(Sp + base + (mb + mi) * 1024 + (o0 ^ (ks * 32)));
}
// fragments f=0,1 at B rows base + f*16 + (cb>>1)*64
__device__ __forceinline__ void loadB2(bf16x8 (&b)[2][2], const __bf16* Sp,
                                       int base, int cb, int o0) {
#pragma unroll
    for (int f = 0; f < 2; f++)
#pragma unroll
        for (int ks = 0; ks < 2; ks++)
            b[f][ks] = *(const bf16x8*)(Sp + base + (f * 16 + (cb >> 1) * 64) * 64 + (o0 ^ (ks * 32)));
}

template<int RB, int CB>
__device__ __forceinline__ void cluster(f32x4 (&acc)[8][4], bf16x8 (&a)[4][2],
                                        bf16x8 (&b)[2][2]) {
    __builtin_amdgcn_s_setprio(1);
#pragma unroll
    for (int mi = 0; mi < 4; mi++)
#pragma unroll
        for (int ni = 0; ni < 2; ni++)
#pragma unroll
            for (int ks = 0; ks < 2; ks++)
                acc[RB + mi][CB + ni] = __builtin_amdgcn_mfma_f32_16x16x32_bf16(
                    a[mi][ks], b[ni][ks], acc[RB + mi][CB + ni], 0, 0, 0);
    __builtin_amdgcn_s_setprio(0);
}

#define FENCE  asm volatile("" ::: "memory")
#define BAR    do { FENCE; __builtin_amdgcn_s_barrier(); FENCE; } while (0)
#define LGKM0  asm volatile("s_waitcnt lgkmcnt(0)" ::: "memory")
#define VM8    asm volatile("s_waitcnt vmcnt(8)" ::: "memory")
#define VM0    asm volatile("s_waitcnt vmcnt(0)" ::: "memory")
#define SCHED0 __builtin_amdgcn_sched_barrier(0)

// stage A/B half HF (0: rows {0-63,128-191}; 1: rows {64-127,192-255}) of
// K-tile kt into buf P.  Per-wave: rowgroups {HF*8+w, HF*8+16+w}.
#define STGA(P, kt, HF) do { \
    gload_lds16(pA + (size_t)((HF) * 64 + w * 8) * DM + (kt) * 64,       &As[P][((HF) * 8 + w) * 512]); \
    gload_lds16(pA + (size_t)((HF) * 64 + 128 + w * 8) * DM + (kt) * 64, &As[P][((HF) * 8 + 16 + w) * 512]); \
} while (0)
#define STGB(P, kt, HF) do { \
    gload_lds16(pB + (size_t)((HF) * 64 + w * 8) * DM + (kt) * 64,       &Bs[P][((HF) * 8 + w) * 512]); \
    gload_lds16(pB + (size_t)((HF) * 64 + 128 + w * 8) * DM + (kt) * 64, &Bs[P][((HF) * 8 + 16 + w) * 512]); \
} while (0)

#define KTILE(kt, P, Q, SG, NX, BC0, BC1, BN0, BN1) do { \
    loadA4(a_hi, &As[P][0], baseA, 4, o0);       /* set2: 8 reads */ \
    SCHED0; \
    cluster<0, 0>(acc, a_lo, BC0); \
    cluster<0, 2>(acc, a_lo, BC1); \
    SCHED0; \
    LGKM0; VM0; BAR; \
    if (SG) { STGA(P, (kt) + 2, 0); STGA(P, (kt) + 2, 1); \
              STGB(P, (kt) + 2, 0); STGB(P, (kt) + 2, 1); } \
    if (NX) { loadA4(a_lo, &As[Q][0], baseA, 0, o0); \
              loadB2(BN0, &Bs[Q][0], baseB, 0, o0); \
              loadB2(BN1, &Bs[Q][0], baseB, 2, o0); } \
    SCHED0; \
    cluster<4, 0>(acc, a_hi, BC0); \
    cluster<4, 2>(acc, a_hi, BC1); \
} while (0)

__global__ __launch_bounds__(512, 2)
void gemm_qkv(const __bf16* __restrict__ A,
              const __bf16* __restrict__ Wq,
              const __bf16* __restrict__ Wk,
              const __bf16* __restrict__ Wv,
              float* __restrict__ out) {
    __shared__ __bf16 As[2][16384];   // 2 x 256x64
    __shared__ __bf16 Bs[2][16384];

    int tid = threadIdx.x;
    int w = tid >> 6, l = tid & 63;
    int wm = w >> 2, wn = w & 3;

    // 2D-clustered XCD mapping (R6, verified)
    int bid = blockIdx.x;
    int x = bid & 7;
    int ridx = bid >> 3;               // 0..95
    int q = ridx >> 5;                 // round 0,1,2
    int s = ridx & 31;
    int mtp, ntp;
    if (q == 0)      { mtp = s >> 3;       ntp = s & 7; }
    else if (q == 1) { mtp = 4 + (s >> 3); ntp = s & 7; }
    else             { mtp = s & 7;        ntp = 8 + (s >> 3); }
    int mt = (x & 3) * 8 + mtp;        // 0..31
    int nt = (x >> 2) * 12 + ntp;      // 0..23
    int mat = nt >> 3, ntb = nt & 7;
    const __bf16* Wp = (mat == 0) ? Wq : (mat == 1) ? Wk : Wv;
    int row0 = mt * 256, colp = ntb * 256;

    // staging base pointers (rule 21: pre-swizzled source, linear LDS dest)
    int lr = l >> 3;
    int lco = ((l & 7) ^ lr) * 8;
    const __bf16* pA = A  + (size_t)(row0 + lr) * DM + lco;
    const __bf16* pB = Wp + (size_t)(colp + lr) * DM + lco;

    // ds_read lane constants (elements); read-side XOR matches write swizzle
    int baseA = (wm * 128 + (l & 15)) * 64;
    int baseB = ((wn & 1) * 32 + (wn >> 1) * 128 + (l & 15)) * 64;
    int o0 = ((l >> 4) * 8) ^ ((l & 7) * 8);

    // prologue: U(0)->buf0 [loads 1-8]; U(1)->buf1 [loads 9-16]
    STGA(0, 0, 0); STGA(0, 0, 1); STGB(0, 0, 0); STGB(0, 0, 1);
    STGA(1, 1, 0); STGA(1, 1, 1); STGB(1, 1, 0); STGB(1, 1, 1);

    f32x4 acc[8][4];
#pragma unroll
    for (int i = 0; i < 8; i++)
#pragma unroll
        for (int j = 0; j < 4; j++)
            acc[i][j] = (f32x4){0.f, 0.f, 0.f, 0.f};

    bf16x8 a_lo[4][2], a_hi[4][2];
    bf16x8 bE0[2][2], bE1[2][2], bO0[2][2], bO1[2][2];

    VM8;          // U(0) landed (the 8 newer = U(1) may be outstanding)
    BAR;
    // set1(0): a_lo + bE from buf0 (consumed by body0's cluster1 via auto-lgkm)
    loadA4(a_lo, &As[0][0], baseA, 0, o0);
    loadB2(bE0, &Bs[0][0], baseB, 0, o0);
    loadB2(bE1, &Bs[0][0], baseB, 2, o0);

#pragma unroll 1
    for (int kt = 0; kt < 28; kt += 2) {
        KTILE(kt,     0, 1, 1, 1, bE0, bE1, bO0, bO1);
        KTILE(kt + 1, 1, 0, 1, 1, bO0, bO1, bE0, bE1);
    }
    KTILE(28, 0, 1, 1, 1, bE0, bE1, bO0, bO1);   // stages U(30)
    KTILE(29, 1, 0, 1, 1, bO0, bO1, bE0, bE1);   // stages U(31)
    KTILE(30, 0, 1, 0, 1, bE0, bE1, bO0, bO1);   // no stage; prefetch set1(31)
    KTILE(31, 1, 0, 0, 0, bO0, bO1, bE0, bE1);   // nothing

    // ---------------- epilogue: head-split layout + fused RoPE ---------------
    // acc[mi][ni] col = (wn&1)*32 + (ni&1)*16 + (wn>>1)*128 + (ni>>1)*64 + (l&15)
    // -> (acc[mi][ni], acc[mi][ni+2]) is the (d, d+64) rotation pair, ni=0,1.
    float* op = out + (size_t)mat * MAT_ELEMS;
    int hd_lo = (wn & 1) * 32 + (l & 15);                 // d for ni=0 (0..63)
    int head = ntb * 2 + (wn >> 1);
    int r_base = row0 + wm * 128 + ((l >> 4) << 2);
    float if0 = exp2f(-0.20762051f * (float)hd_lo);        // 10000^(-d/64)
    float if1 = exp2f(-0.20762051f * (float)(hd_lo + 16));

    if (mat < 2) {
#pragma unroll
        for (int mi = 0; mi < 8; mi++) {
#pragma unroll
            for (int j = 0; j < 4; j++) {
                int r = r_base + mi * 16 + j;
                int b = r >> 12, n = r & 4095;
                float fn = (float)n;
                float* rowp = op + ((size_t)((b * NH + head) * NSEQ + n)) * HD;
#pragma unroll
                for (int ni = 0; ni < 2; ni++) {
                    float lo = acc[mi][ni][j], hi = acc[mi][ni + 2][j];
                    float sv, cv;
                    __sincosf(fn * (ni ? if1 : if0), &sv, &cv);
                    rowp[hd_lo + ni * 16]      = lo * cv - hi * sv;
                    rowp[hd_lo + ni * 16 + 64] = hi * cv + lo * sv;
                }
            }
        }
    } else {
#pragma unroll
        for (int mi = 0; mi < 8; mi++) {
#pragma unroll
            for (int j = 0; j < 4; j++) {
                int r = r_base + mi * 16 + j;
                int b = r >> 12, n = r & 4095;
                float* rowp = op + ((size_t)((b * NH + head) * NSEQ + n)) * HD;
#pragma unroll
                for (int ni = 0; ni < 2; ni++) {
                    rowp[hd_lo + ni * 16]      = acc[mi][ni][j];
                    rowp[hd_lo + ni * 16 + 64] = acc[mi][ni + 2][j];
                }
            }
        }
    }
}

// ---------------------------------------------------------------------------
extern "C" void kernel_launch(void* const* d_in, const int* in_sizes, int n_in,
                              void* d_out, int out_size, void* d_ws, size_t ws_size,
                              hipStream_t stream) {
    const float* x  = (const float*)d_in[0];
    const float* g  = (const float*)d_in[1];
    const float* be = (const float*)d_in[2];
    const float* wq = (const float*)d_in[3];
    const float* wk = (const float*)d_in[4];
    const float* wv = (const float*)d_in[5];
    float* out = (float*)d_out;

    char* ws = (char*)d_ws;
    __bf16* xnb = (__bf16*)ws;                                   // 32 MB
    __bf16* wb  = (__bf16*)(ws + 33554432);                      // 24 MB (q,k,v)

    lncvt_kernel<<<NROWS + 6144, 256, 0, stream>>>(x, g, be, wq, wk, wv, xnb, wb);
    gemm_qkv<<<768, 512, 0, stream>>>(xnb, wb, wb + 4194304, wb + 8388608, out);
}

// Round 17
// 221.387 us; speedup vs baseline: 3.4409x; 3.4409x over previous
//
#include <hip/hip_runtime.h>
#include <hip/hip_bf16.h>

// Fused LN -> QKV projection (bf16 MFMA, 256^2, 4-phase schedule with
// m201-style single counted vmcnt per K-tile, 2D-clustered XCD mapping),
// RoPE fused into the GEMM epilogue.  [R12 best-known configuration]
// x:(2,4096,2048) f32; wq/wk/wv:(2048,2048) f32 row-major [e][d]; out: q,k,v
// each (2,16,4096,128) f32 concatenated.

typedef float f32x4 __attribute__((ext_vector_type(4)));
typedef __bf16 bf16x8 __attribute__((ext_vector_type(8)));
typedef __bf16 bf16x4 __attribute__((ext_vector_type(4)));

#define DM    2048
#define NSEQ  4096
#define NH    16
#define HD    128
#define NROWS 8192
#define MAT_ELEMS (2ull*NH*NSEQ*HD)

// ---------- async global->LDS (16B/lane, wave-uniform LDS base) --------------
typedef __attribute__((address_space(1))) const void GV;
typedef __attribute__((address_space(3))) void LV;
__device__ __forceinline__ void gload_lds16(const void* g, void* l) {
    __builtin_amdgcn_global_load_lds((GV*)g, (LV*)l, 16, 0, 0);
}

// ------------- LayerNorm + weight f32->bf16 cast, single launch --------------
__global__ __launch_bounds__(256)
void lncvt_kernel(const float* __restrict__ x, const float* __restrict__ g,
                  const float* __restrict__ be,
                  const float* __restrict__ wq, const float* __restrict__ wk,
                  const float* __restrict__ wv,
                  __bf16* __restrict__ xnb, __bf16* __restrict__ wb) {
    int bid = blockIdx.x;
    int tid = threadIdx.x;
    if (bid < NROWS) {
        int row = bid;
        const float4* xr = (const float4*)(x + (size_t)row * DM);
        float4 v0 = xr[tid];
        float4 v1 = xr[tid + 256];
        float s  = v0.x + v0.y + v0.z + v0.w + v1.x + v1.y + v1.z + v1.w;
        float ss = v0.x*v0.x + v0.y*v0.y + v0.z*v0.z + v0.w*v0.w
                 + v1.x*v1.x + v1.y*v1.y + v1.z*v1.z + v1.w*v1.w;
#pragma unroll
        for (int o = 32; o > 0; o >>= 1) {
            s  += __shfl_down(s, o);
            ss += __shfl_down(ss, o);
        }
        __shared__ float red[10];
        int wave = tid >> 6, lane = tid & 63;
        if (lane == 0) { red[wave] = s; red[4 + wave] = ss; }
        __syncthreads();
        if (tid == 0) {
            float S  = red[0] + red[1] + red[2] + red[3];
            float SS = red[4] + red[5] + red[6] + red[7];
            float mu  = S * (1.0f / DM);
            float var = SS * (1.0f / DM) - mu * mu;
            red[8] = mu;
            red[9] = rsqrtf(var + 1e-5f);
        }
        __syncthreads();
        float mu = red[8], rs = red[9];

        const float4* gp = (const float4*)g;
        const float4* bp = (const float4*)be;
        bf16x4* orow = (bf16x4*)(xnb + (size_t)row * DM);
        {
            float4 g0 = gp[tid], b0 = bp[tid];
            bf16x4 o;
            o[0] = (__bf16)((v0.x - mu) * rs * g0.x + b0.x);
            o[1] = (__bf16)((v0.y - mu) * rs * g0.y + b0.y);
            o[2] = (__bf16)((v0.z - mu) * rs * g0.z + b0.z);
            o[3] = (__bf16)((v0.w - mu) * rs * g0.w + b0.w);
            orow[tid] = o;
        }
        {
            float4 g1 = gp[tid + 256], b1 = bp[tid + 256];
            bf16x4 o;
            o[0] = (__bf16)((v1.x - mu) * rs * g1.x + b1.x);
            o[1] = (__bf16)((v1.y - mu) * rs * g1.y + b1.y);
            o[2] = (__bf16)((v1.z - mu) * rs * g1.z + b1.z);
            o[3] = (__bf16)((v1.w - mu) * rs * g1.w + b1.w);
            orow[tid + 256] = o;
        }
    } else {
        int cb = bid - NROWS;                   // 0..6143
        const float* a = (cb < 2048) ? wq : (cb < 4096) ? wk : wv;
        size_t base = ((size_t)(cb & 2047) * 256 + tid) * 8;
        float4 v0 = *(const float4*)(a + base);
        float4 v1 = *(const float4*)(a + base + 4);
        bf16x8 r;
        r[0] = (__bf16)v0.x; r[1] = (__bf16)v0.y; r[2] = (__bf16)v0.z; r[3] = (__bf16)v0.w;
        r[4] = (__bf16)v1.x; r[5] = (__bf16)v1.y; r[6] = (__bf16)v1.z; r[7] = (__bf16)v1.w;
        *(bf16x8*)(wb + (size_t)(cb >> 11) * 4194304 + base) = r;
    }
}

// =====================  256x256 4-phase QKV GEMM  ============================
// Tile 256x256, BK=64, 8 waves (2Mx4N), LDS 128KiB dbuf, XOR-swizzle.
// Units: U0=A rows{0-63,128-191}, U1=A rows{64-127,192-255}; U2/U3 = B same.
// Reads: ph0 = U0(A m0-3) + U2(B cb0); ph1 = U3(B cb2); ph2 = U1(A m4-7);
// ph3 = none (registers only).
// Stages: ph0 -> U1(kt+1)->Q; ph1 -> U0(kt+2)->P; ph2 -> U2(kt+2)->P;
// ph3 -> U3(kt+2)->P.  (R6 placement, WAR-proven.)
//
// Waits: ONE vmcnt per K-tile, at ph3 after its stage:
//   steady: covers U1(kt+1) [staged ph0(kt)]; loads after = ph1+ph2+ph3 = 6
//     -> vmcnt(6).  All older units (U0/U2/U3(kt+1), staged kt-1) implied.
//   pre-loop: 14 prologue loads, kt0 needs loads 1-8 -> vmcnt(6) + BAR.
//   tails: kt30 stages only U1(31) at ph0 -> W3 = vmcnt(0); kt31 none.
// Each opening barrier is followed by explicit lgkmcnt(0) + sched_barrier(0).

__device__ __forceinline__ void loadA4(bf16x8 (&a)[4][2], const __bf16* Sp,
                                       int base, int mb, int o0) {
#pragma unroll
    for (int mi = 0; mi < 4; mi++)
#pragma unroll
        for (int ks = 0; ks < 2; ks++)
            a[mi][ks] = *(const bf16x8*)(Sp + base + (mb + mi) * 1024 + (o0 ^ (ks * 32)));
}
// fragments f=0,1 at B rows base + f*16 + (cb>>1)*64
__device__ __forceinline__ void loadB2(bf16x8 (&b)[2][2], const __bf16* Sp,
                                       int base, int cb, int o0) {
#pragma unroll
    for (int f = 0; f < 2; f++)
#pragma unroll
        for (int ks = 0; ks < 2; ks++)
            b[f][ks] = *(const bf16x8*)(Sp + base + (f * 16 + (cb >> 1) * 64) * 64 + (o0 ^ (ks * 32)));
}

template<int RB, int CB>
__device__ __forceinline__ void cluster(f32x4 (&acc)[8][4], bf16x8 (&a)[4][2],
                                        bf16x8 (&b)[2][2]) {
    __builtin_amdgcn_s_setprio(1);
#pragma unroll
    for (int mi = 0; mi < 4; mi++)
#pragma unroll
        for (int ni = 0; ni < 2; ni++)
#pragma unroll
            for (int ks = 0; ks < 2; ks++)
                acc[RB + mi][CB + ni] = __builtin_amdgcn_mfma_f32_16x16x32_bf16(
                    a[mi][ks], b[ni][ks], acc[RB + mi][CB + ni], 0, 0, 0);
    __builtin_amdgcn_s_setprio(0);
}

#define FENCE asm volatile("" ::: "memory")
#define BAR   do { FENCE; __builtin_amdgcn_s_barrier(); FENCE; } while (0)
// opening barrier: sync, then hard lgkm gate before MFMA (template pattern)
#define BARO  do { BAR; asm volatile("s_waitcnt lgkmcnt(0)" ::: "memory"); \
                   __builtin_amdgcn_sched_barrier(0); } while (0)
#define VM6   asm volatile("s_waitcnt vmcnt(6)" ::: "memory")
#define VM0   asm volatile("s_waitcnt vmcnt(0)" ::: "memory")
#define VMX   do {} while (0)

// stage A/B half HF (0: rows {0-63,128-191}; 1: rows {64-127,192-255}) of
// K-tile kt into buf P.  Per-wave: rowgroups {HF*8+w, HF*8+16+w}.
#define STGA(P, kt, HF) do { \
    gload_lds16(pA + (size_t)((HF) * 64 + w * 8) * DM + (kt) * 64,       &As[P][((HF) * 8 + w) * 512]); \
    gload_lds16(pA + (size_t)((HF) * 64 + 128 + w * 8) * DM + (kt) * 64, &As[P][((HF) * 8 + 16 + w) * 512]); \
} while (0)
#define STGB(P, kt, HF) do { \
    gload_lds16(pB + (size_t)((HF) * 64 + w * 8) * DM + (kt) * 64,       &Bs[P][((HF) * 8 + w) * 512]); \
    gload_lds16(pB + (size_t)((HF) * 64 + 128 + w * 8) * DM + (kt) * 64, &Bs[P][((HF) * 8 + 16 + w) * 512]); \
} while (0)

#define KTILE(kt, P, Q, SG0, SG1, SG2, SG3, W3) do { \
    /* ph0: quad (0,0) */ \
    loadA4(a,  &As[P][0], baseA, 0, o0); \
    loadB2(b0, &Bs[P][0], baseB, 0, o0); \
    if (SG0) STGA(Q, (kt) + 1, 1);               /* U1(kt+1) */ \
    BARO; cluster<0, 0>(acc, a, b0); BAR; \
    /* ph1: quad (0,2) */ \
    loadB2(b1, &Bs[P][0], baseB, 2, o0); \
    if (SG1) STGA(P, (kt) + 2, 0);               /* U0(kt+2) */ \
    BARO; cluster<0, 2>(acc, a, b1); BAR; \
    /* ph2: quad (4,2) */ \
    loadA4(a, &As[P][0], baseA, 4, o0); \
    if (SG2) STGB(P, (kt) + 2, 0);               /* U2(kt+2) */ \
    BARO; cluster<4, 2>(acc, a, b1); BAR; \
    /* ph3: quad (4,0) */ \
    if (SG3) STGB(P, (kt) + 2, 1);               /* U3(kt+2) */ \
    W3; \
    BARO; cluster<4, 0>(acc, a, b0); BAR; \
} while (0)

__global__ __launch_bounds__(512, 2)
void gemm_qkv(const __bf16* __restrict__ A,
              const __bf16* __restrict__ Wq,
              const __bf16* __restrict__ Wk,
              const __bf16* __restrict__ Wv,
              float* __restrict__ out) {
    __shared__ __bf16 As[2][16384];   // 2 x 256x64
    __shared__ __bf16 Bs[2][16384];

    int tid = threadIdx.x;
    int w = tid >> 6, l = tid & 63;
    int wm = w >> 2, wn = w & 3;

    // 2D-clustered XCD mapping (R6, verified): xcd owns 8mt x 12nt region;
    // each round's 32 co-resident blocks form a 4x8 / 8x4 cluster in L2.
    int bid = blockIdx.x;
    int x = bid & 7;
    int ridx = bid >> 3;               // 0..95
    int q = ridx >> 5;                 // round 0,1,2
    int s = ridx & 31;
    int mtp, ntp;
    if (q == 0)      { mtp = s >> 3;       ntp = s & 7; }
    else if (q == 1) { mtp = 4 + (s >> 3); ntp = s & 7; }
    else             { mtp = s & 7;        ntp = 8 + (s >> 3); }
    int mt = (x & 3) * 8 + mtp;        // 0..31
    int nt = (x >> 2) * 12 + ntp;      // 0..23
    int mat = nt >> 3, ntb = nt & 7;
    const __bf16* Wp = (mat == 0) ? Wq : (mat == 1) ? Wk : Wv;
    int row0 = mt * 256, colp = ntb * 256;

    // staging base pointers: lane covers row lr of each 8-row group, 16B at
    // pre-swizzled col ((l&7)^(l>>3))*16B  (rule 21: swizzle source, linear dest)
    int lr = l >> 3;
    int lco = ((l & 7) ^ lr) * 8;
    const __bf16* pA = A  + (size_t)(row0 + lr) * DM + lco;
    const __bf16* pB = Wp + (size_t)(colp + lr) * DM + lco;

    // ds_read lane constants (elements); read-side XOR matches write swizzle
    int baseA = (wm * 128 + (l & 15)) * 64;
    int baseB = ((wn & 1) * 32 + (wn >> 1) * 128 + (l & 15)) * 64;
    int o0 = ((l >> 4) * 8) ^ ((l & 7) * 8);

    // prologue: U0,U1,U2,U3(kt0)->buf0 [loads 1-8]; U0,U2,U3(kt1)->buf1 [9-14]
    STGA(0, 0, 0); STGB(0, 0, 0); STGB(0, 0, 1); STGA(0, 0, 1);
    STGA(1, 1, 0); STGB(1, 1, 0); STGB(1, 1, 1);

    f32x4 acc[8][4];
#pragma unroll
    for (int i = 0; i < 8; i++)
#pragma unroll
        for (int j = 0; j < 4; j++)
            acc[i][j] = (f32x4){0.f, 0.f, 0.f, 0.f};

    bf16x8 a[4][2], b0[2][2], b1[2][2];

    VM6;          // loads 1-8 = all of kt0 landed before first ds_read
    BAR;

#pragma unroll 1
    for (int kt = 0; kt < 30; kt += 2) {
        KTILE(kt,     0, 1, 1, 1, 1, 1, VM6);
        KTILE(kt + 1, 1, 0, 1, 1, 1, 1, VM6);
    }
    KTILE(30, 0, 1, 1, 0, 0, 0, VM0);   // stages only U1(31); drain
    KTILE(31, 1, 0, 0, 0, 0, 0, VMX);

    // ---------------- epilogue: head-split layout + fused RoPE ---------------
    // acc[mi][ni] col = (wn&1)*32 + (ni&1)*16 + (wn>>1)*128 + (ni>>1)*64 + (l&15)
    // -> (acc[mi][ni], acc[mi][ni+2]) is the (d, d+64) rotation pair, ni=0,1.
    float* op = out + (size_t)mat * MAT_ELEMS;
    int hd_lo = (wn & 1) * 32 + (l & 15);                 // d for ni=0 (0..63)
    int head = ntb * 2 + (wn >> 1);
    int r_base = row0 + wm * 128 + ((l >> 4) << 2);
    float if0 = exp2f(-0.20762051f * (float)hd_lo);        // 10000^(-d/64)
    float if1 = exp2f(-0.20762051f * (float)(hd_lo + 16));

    if (mat < 2) {
#pragma unroll
        for (int mi = 0; mi < 8; mi++) {
#pragma unroll
            for (int j = 0; j < 4; j++) {
                int r = r_base + mi * 16 + j;
                int b = r >> 12, n = r & 4095;
                float fn = (float)n;
                float* rowp = op + ((size_t)((b * NH + head) * NSEQ + n)) * HD;
#pragma unroll
                for (int ni = 0; ni < 2; ni++) {
                    float lo = acc[mi][ni][j], hi = acc[mi][ni + 2][j];
                    float sv, cv;
                    __sincosf(fn * (ni ? if1 : if0), &sv, &cv);
                    rowp[hd_lo + ni * 16]      = lo * cv - hi * sv;
                    rowp[hd_lo + ni * 16 + 64] = hi * cv + lo * sv;
                }
            }
        }
    } else {
#pragma unroll
        for (int mi = 0; mi < 8; mi++) {
#pragma unroll
            for (int j = 0; j < 4; j++) {
                int r = r_base + mi * 16 + j;
                int b = r >> 12, n = r & 4095;
                float* rowp = op + ((size_t)((b * NH + head) * NSEQ + n)) * HD;
#pragma unroll
                for (int ni = 0; ni < 2; ni++) {
                    rowp[hd_lo + ni * 16]      = acc[mi][ni][j];
                    rowp[hd_lo + ni * 16 + 64] = acc[mi][ni + 2][j];
                }
            }
        }
    }
}

// ---------------------------------------------------------------------------
extern "C" void kernel_launch(void* const* d_in, const int* in_sizes, int n_in,
                              void* d_out, int out_size, void* d_ws, size_t ws_size,
                              hipStream_t stream) {
    const float* x  = (const float*)d_in[0];
    const float* g  = (const float*)d_in[1];
    const float* be = (const float*)d_in[2];
    const float* wq = (const float*)d_in[3];
    const float* wk = (const float*)d_in[4];
    const float* wv = (const float*)d_in[5];
    float* out = (float*)d_out;

    char* ws = (char*)d_ws;
    __bf16* xnb = (__bf16*)ws;                                   // 32 MB
    __bf16* wb  = (__bf16*)(ws + 33554432);                      // 24 MB (q,k,v)

    lncvt_kernel<<<NROWS + 6144, 256, 0, stream>>>(x, g, be, wq, wk, wv, xnb, wb);
    gemm_qkv<<<768, 512, 0, stream>>>(xnb, wb, wb + 4194304, wb + 8388608, out);
}